// Round 13
// baseline (151.117 us; speedup 1.0000x reference)
//
#include <hip/hip_runtime.h>
#include <math.h>

#define B_   1024
#define M_   10
#define M1_  11
#define DIM_ 128
#define NW_  201                    // real weight rows; r >= 201 -> zero matrix
#define NQUAD_ (4*B_*M1_*M1_)       // 495616 (case,b,j,k) quadruples
#define IPB_  64                    // items per GEMM chunk
#define SLOTS_ 2048                 // item slots per relation type (cnt ~800 max)
#define SCATB_ 242                  // scatter blocks (x256 thr x8 quads)
#define WTILES_ ((NW_+1)*16)        // wconv: one 32x32 tile per block (entity W + Wr)
#define MAXCHK_ (NW_ + NQUAD_/IPB_) // 7945 upper bound on chunks

typedef __attribute__((ext_vector_type(8))) short bf16x8;
typedef __attribute__((ext_vector_type(4))) float f32x4;

struct GatherPtrs {
    const int* center[4];
    const int* adj[4];
    const int* nn[4];
    const int* Rt[4];
    const float* Dm[4];
};

struct RelPtrs {
    const int* center[2];
    const int* adj2[2];
    const float* A[2];
};

__device__ __forceinline__ unsigned short f2bf(float f) {
    union { float f; unsigned u; } v; v.f = f;
    const unsigned r = v.u + 0x7FFFu + ((v.u >> 16) & 1u);   // RNE
    return (unsigned short)(r >> 16);
}

// ---------------------------------------------------------------------------
// Prep: blocks [0,SCATB_)            : scatter with pre-resolved row/D
//       blocks [SCATB_, +WTILES_)    : weight transpose + bf16 (W and Wr)
// The LAST scatter block to finish also builds the front-packed chunk table
// (reads counts via atomicAdd(.,0) -> coherent across XCDs).
// ---------------------------------------------------------------------------
__global__ __launch_bounds__(256)
void prep_kernel(GatherPtrs gp,
                 const float* __restrict__ W, const float* __restrict__ Wr,
                 unsigned short* __restrict__ WT,
                 int* __restrict__ cursor, int* __restrict__ done,
                 int2* __restrict__ itemsEQ, float* __restrict__ itemsD,
                 int* __restrict__ chunkTab, int* __restrict__ nchunks)
{
    __shared__ int lh[NW_];
    __shared__ int lbase[NW_];
    __shared__ float tile[32][33];
    __shared__ int sLast;
    __shared__ int nchS[NW_];
    __shared__ int bsS[NW_ + 1];
    const int tid = threadIdx.x;
    const int bid = blockIdx.x;

    if (bid < SCATB_) {
        if (tid < NW_) lh[tid] = 0;
        __syncthreads();
        int rr[8], rk[8], ei[8], qv[8];
        float dv[8];
        #pragma unroll
        for (int s = 0; s < 8; ++s) {
            const int idx = bid * 2048 + s * 256 + tid;
            const int c = idx / (B_ * M1_ * M1_);
            const int rem = idx % (B_ * M1_ * M1_);
            const int b = rem / (M1_ * M1_);
            const int jk = rem % (M1_ * M1_);
            const int j = jk / M1_, k = jk % M1_;
            const int n = gp.nn[c][b];
            rr[s] = -1;
            if (j <= n && k <= n) {
                const int r = gp.Rt[c][rem];
                if (r < NW_) {
                    rr[s] = r;
                    rk[s] = atomicAdd(&lh[r], 1);
                    const int eidx = (j == 0) ? gp.center[c][b]
                                              : gp.adj[c][b * M_ + (j - 1)];
                    ei[s] = (eidx << 1) | (j != 0);
                    qv[s] = idx;                       // q == linear quadruple idx
                    dv[s] = gp.Dm[c][rem];
                }
            }
        }
        __syncthreads();
        if (tid < NW_) lbase[tid] = lh[tid] ? atomicAdd(&cursor[tid], lh[tid]) : 0;
        __syncthreads();
        #pragma unroll
        for (int s = 0; s < 8; ++s)
            if (rr[s] >= 0) {
                const int slot = lbase[rr[s]] + rk[s];
                if (slot < SLOTS_) {
                    itemsEQ[rr[s] * SLOTS_ + slot] = make_int2(ei[s], qv[s]);
                    itemsD[rr[s] * SLOTS_ + slot] = dv[s];
                }
            }
        // ---- last-block chunk build ----
        __threadfence();
        __syncthreads();
        if (tid == 0) sLast = (atomicAdd(done, 1) == SCATB_ - 1);
        __syncthreads();
        if (sLast) {
            if (tid < NW_) {
                const int cnt = min(atomicAdd(&cursor[tid], 0), SLOTS_);
                nchS[tid] = (cnt + IPB_ - 1) >> 6;
            }
            __syncthreads();
            if (tid == 0) {
                int acc = 0;
                for (int i = 0; i < NW_; ++i) { bsS[i] = acc; acc += nchS[i]; }
                nchunks[0] = acc;
            }
            __syncthreads();
            if (tid < NW_)
                for (int c = 0; c < nchS[tid]; ++c)
                    chunkTab[bsS[tid] + c] = (tid << 16) | c;
        }
    } else {
        const int tl = bid - SCATB_;
        const int t = tl >> 4, sub = tl & 15;
        const int bd = (sub >> 2) * 32, be = (sub & 3) * 32;
        const float* Ws = (t < NW_) ? (W + (size_t)t * DIM_ * DIM_) : Wr;
        unsigned short* Wd = WT + (size_t)t * DIM_ * DIM_;
        const int tx = tid & 31, ty = tid >> 5;
        #pragma unroll
        for (int r = 0; r < 32; r += 8)
            tile[r + ty][tx] = Ws[(bd + r + ty) * DIM_ + be + tx];
        __syncthreads();
        #pragma unroll
        for (int r = 0; r < 32; r += 8)
            Wd[(be + r + ty) * DIM_ + bd + tx] = f2bf(tile[tx][r + ty]);
    }
}

// ---------------------------------------------------------------------------
// MFMA grouped GEMM: dense front-packed grid (chunkTab), one chunk per block.
// Stage chain: itemsEQ (L2-warm) -> embedding row. No W staging (B-fragments
// straight from L2-resident bf16 WT). D applied in f32 epilogue.
// ---------------------------------------------------------------------------
template <bool FAST>
__global__ __launch_bounds__(256)
void rgcn_gemm(const float* __restrict__ ent_emb,
               const float* __restrict__ ent_ctx,
               const unsigned short* __restrict__ WT,   // [t][e][d] bf16
               const int2* __restrict__ itemsEQ,        // [t][SLOTS_]
               const float* __restrict__ itemsD,        // [t][SLOTS_]
               const int* __restrict__ cursor,
               const int* __restrict__ chunkTab,
               const int* __restrict__ nchunks,
               _Float16* __restrict__ partial,
               float* __restrict__ vent)
{
    __shared__ unsigned short sH[IPB_ * DIM_];   // 16 KB, [item][d] swizzled
    __shared__ int sQ[IPB_];
    __shared__ float sD[IPB_];

    const int bid = blockIdx.x;
    if (bid >= nchunks[0]) return;
    const int ent = chunkTab[bid];
    const int t = ent >> 16, ch = ent & 0xffff;
    const int cnt = min(cursor[t], SLOTS_);
    const int istart = ch * IPB_;
    const int nItems = min(IPB_, cnt - istart);
    const int tid = threadIdx.x;
    const int2* eqBase = itemsEQ + t * SLOTS_ + istart;

    #pragma unroll
    for (int it4 = 0; it4 < 4; ++it4) {
        const int m = it4 * 256 + tid;
        const int it = m >> 4, chd = m & 15;
        uint4 pkd;
        if (it < nItems) {
            const int2 eq = eqBase[it];
            if (chd == 0) {
                sQ[it] = eq.y;
                sD[it] = itemsD[t * SLOTS_ + istart + it];
            }
            const float* srow = (eq.x & 1)
                ? ent_ctx + (size_t)(eq.x >> 1) * DIM_
                : ent_emb + (size_t)(eq.x >> 1) * DIM_;
            const float4* s4 = (const float4*)srow + chd * 2;
            const float4 v0 = s4[0], v1 = s4[1];
            pkd.x = (unsigned)f2bf(v0.x) | ((unsigned)f2bf(v0.y) << 16);
            pkd.y = (unsigned)f2bf(v0.z) | ((unsigned)f2bf(v0.w) << 16);
            pkd.z = (unsigned)f2bf(v1.x) | ((unsigned)f2bf(v1.y) << 16);
            pkd.w = (unsigned)f2bf(v1.z) | ((unsigned)f2bf(v1.w) << 16);
        } else {
            if (chd == 0) { sQ[it] = -1; sD[it] = 0.f; }
            pkd.x = pkd.y = pkd.z = pkd.w = 0u;
        }
        const int so = it * 256 + ((chd * 16) ^ ((it & 7) << 4));
        *reinterpret_cast<uint4*>(reinterpret_cast<char*>(sH) + so) = pkd;
    }
    __syncthreads();

    // 4 waves; wave w owns n-tiles {2w, 2w+1}, all 4 m-tiles.
    const int w = tid >> 6, l = tid & 63;
    const int lr = l & 15, lk = l >> 4;
    const unsigned short* Wp = WT + (size_t)t * DIM_ * DIM_;
    const f32x4 z = {0.f, 0.f, 0.f, 0.f};
    f32x4 acc[4][2];
    #pragma unroll
    for (int mi = 0; mi < 4; ++mi) { acc[mi][0] = z; acc[mi][1] = z; }

    #pragma unroll
    for (int kb = 0; kb < 4; ++kb) {
        const int o = kb * 64 + lk * 16;
        bf16x8 af[4], bfr[2];
        #pragma unroll
        for (int ni = 0; ni < 2; ++ni) {
            const int row = (2 * w + ni) * 16 + lr;
            bfr[ni] = *reinterpret_cast<const bf16x8*>(Wp + (size_t)row * DIM_ + kb * 32 + lk * 8);
        }
        #pragma unroll
        for (int mi = 0; mi < 4; ++mi) {
            const int row = mi * 16 + lr;
            af[mi] = *reinterpret_cast<const bf16x8*>(
                reinterpret_cast<const char*>(sH) + row * 256 + (o ^ ((row & 7) << 4)));
        }
        #pragma unroll
        for (int mi = 0; mi < 4; ++mi)
            #pragma unroll
            for (int ni = 0; ni < 2; ++ni)
                acc[mi][ni] = __builtin_amdgcn_mfma_f32_16x16x32_bf16(
                    af[mi], bfr[ni], acc[mi][ni], 0, 0, 0);
    }

    #pragma unroll
    for (int mi = 0; mi < 4; ++mi) {
        #pragma unroll
        for (int jj = 0; jj < 4; ++jj) {
            const int it = mi * 16 + lk * 4 + jj;
            const int q = sQ[it];
            if (q >= 0) {
                const float d = sD[it];
                #pragma unroll
                for (int ni = 0; ni < 2; ++ni) {
                    const int col = (2 * w + ni) * 16 + lr;
                    const float val = acc[mi][ni][jj] * d;
                    if (FAST) {
                        partial[(size_t)q * DIM_ + col] = (_Float16)val;
                    } else {
                        unsafeAtomicAdd(vent + (size_t)(q / M1_) * DIM_ + col, val);
                    }
                }
            }
        }
    }
}

// ---------------------------------------------------------------------------
// Epilogue: grid B, 768 threads = 6 groups of 128.
//   groups 0..3 : entity subgraph pool (fp16 partial gather)
//   groups 4,5  : relation GCN via MFMA + pool
// then score (gating + two L2 norms) in the same block via LDS.
// ALL __syncthreads are top-level (6 barriers, uniform across groups).
// ---------------------------------------------------------------------------
template <bool FAST>
__global__ __launch_bounds__(768)
void epi_kernel(GatherPtrs gp, RelPtrs rp,
                const float* __restrict__ ent_emb,
                const float* __restrict__ rel_emb,
                const float* __restrict__ rel_ctx,
                const unsigned short* __restrict__ WT,
                const float* __restrict__ v_ent,
                const float* __restrict__ v_rel,
                const float* __restrict__ gate_e,
                const float* __restrict__ gate_r,
                const _Float16* __restrict__ partial,  // FAST
                const float* __restrict__ vent,        // !FAST
                float* __restrict__ out)
{
    __shared__ float sSG[6][DIM_];
    __shared__ float sred[6][2][M1_];
    __shared__ int   sRt[4][M1_ * M1_];
    __shared__ float sA[2][M1_ * M1_];
    __shared__ unsigned short sAH[2][16 * DIM_];
    __shared__ float sOut[2][M1_][DIM_];
    __shared__ float sredS[12][2];

    const int b = blockIdx.x;
    const int g = threadIdx.x >> 7;      // 0..5
    const int e = threadIdx.x & 127;

    float vm[M1_];
    float h[M1_];
    float o, vkey;

    // ---- phase A: stage indices / A / h; load center vector ----
    if (g < 4) {
        if (FAST && e < M1_ * M1_) sRt[g][e] = gp.Rt[g][b * (M1_ * M1_) + e];
        o = ent_emb[(size_t)gp.center[g][b] * DIM_ + e];
        vkey = v_ent[e];
    } else {
        const int cse = g - 4;
        const int* adj2 = rp.adj2[cse];
        o = rel_emb[(size_t)rp.center[cse][b] * DIM_ + e];
        h[0] = o;
        #pragma unroll
        for (int j = 1; j < M1_; ++j) {
            const int a0 = adj2[((b * M_) + (j - 1)) * 2 + 0];
            const int a1 = adj2[((b * M_) + (j - 1)) * 2 + 1];
            h[j] = rel_ctx[(size_t)a0 * DIM_ + e] + rel_ctx[(size_t)a1 * DIM_ + e];
        }
        if (e < M1_ * M1_) sA[cse][e] = rp.A[cse][b * (M1_ * M1_) + e];
        vkey = v_rel[e];
    }
    __syncthreads();   // 1

    // ---- phase B: rel AH -> bf16 swizzled A-tile ----
    if (g >= 4) {
        const int cse = g - 4;
        #pragma unroll
        for (int i = 0; i < M1_; ++i) {
            float s = 0.f;
            #pragma unroll
            for (int jj = 0; jj < M1_; ++jj) s += sA[cse][i * M1_ + jj] * h[jj];
            *reinterpret_cast<unsigned short*>(
                reinterpret_cast<char*>(sAH[cse]) + i * 256 + ((2 * e) ^ ((i & 7) << 4))) = f2bf(s);
        }
        #pragma unroll
        for (int i = M1_; i < 16; ++i)
            *reinterpret_cast<unsigned short*>(
                reinterpret_cast<char*>(sAH[cse]) + i * 256 + ((2 * e) ^ ((i & 7) << 4))) = 0;
    }
    __syncthreads();   // 2

    // ---- phase C: ent gather vm  ||  rel MFMA -> sOut ----
    if (g < 4) {
        const int n = gp.nn[g][b];
        if (FAST) {
            #pragma unroll
            for (int j = 0; j < M1_; ++j) {
                float s = 0.f;
                if (j <= n) {   // group-uniform branch
                    const int base = (g * B_ + b) * (M1_ * M1_) + j * M1_;
                    #pragma unroll
                    for (int k = 0; k < M1_; ++k) {
                        const float v = (float)partial[(size_t)(base + k) * DIM_ + e];
                        s += (k <= n && sRt[g][j * M1_ + k] < NW_) ? v : 0.f;
                    }
                    s = fmaxf(s, 0.f);
                }
                vm[j] = s;
            }
        } else {
            const float* vmat = vent + ((size_t)(g * B_ + b)) * M1_ * DIM_;
            #pragma unroll
            for (int j = 0; j < M1_; ++j)
                vm[j] = (j <= n) ? fmaxf(vmat[j * DIM_ + e], 0.f) : 0.f;
        }
    } else {
        const int cse = g - 4;
        const int w = e >> 6, l = e & 63;
        const int lr = l & 15, lk = l >> 4;
        const unsigned short* WrT = WT + (size_t)NW_ * DIM_ * DIM_;
        const f32x4 z = {0.f, 0.f, 0.f, 0.f};
        f32x4 acc[4] = {z, z, z, z};
        #pragma unroll
        for (int kb = 0; kb < 4; ++kb) {
            const bf16x8 af = *reinterpret_cast<const bf16x8*>(
                reinterpret_cast<const char*>(sAH[cse]) + lr * 256 + ((kb * 64 + lk * 16) ^ ((lr & 7) << 4)));
            #pragma unroll
            for (int ni = 0; ni < 4; ++ni) {
                const int cb = w * 4 + ni;
                const bf16x8 bfr = *reinterpret_cast<const bf16x8*>(
                    WrT + (size_t)(cb * 16 + lr) * DIM_ + kb * 32 + lk * 8);
                acc[ni] = __builtin_amdgcn_mfma_f32_16x16x32_bf16(af, bfr, acc[ni], 0, 0, 0);
            }
        }
        #pragma unroll
        for (int ni = 0; ni < 4; ++ni) {
            const int col = (w * 4 + ni) * 16 + lr;
            #pragma unroll
            for (int jj = 0; jj < 4; ++jj) {
                const int i = lk * 4 + jj;
                if (i < M1_) sOut[cse][i][col] = fmaxf(acc[ni][jj], 0.f);
            }
        }
    }
    __syncthreads();   // 3

    // ---- phase D: attention pool (all 6 groups) ----
    if (g >= 4) {
        #pragma unroll
        for (int i = 0; i < M1_; ++i) vm[i] = sOut[g - 4][i][e];
    }
    float p[M1_];
    #pragma unroll
    for (int j = 0; j < M1_; ++j) p[j] = fmaxf(vm[j] * o, 0.f) * vkey;
    #pragma unroll
    for (int off = 32; off; off >>= 1)
        #pragma unroll
        for (int i = 0; i < M1_; ++i) p[i] += __shfl_xor(p[i], off, 64);
    if ((e & 63) == 0) {
        #pragma unroll
        for (int i = 0; i < M1_; ++i) sred[g][e >> 6][i] = p[i];
    }
    __syncthreads();   // 4
    {
        float sc[M1_];
        #pragma unroll
        for (int i = 0; i < M1_; ++i) sc[i] = sred[g][0][i] + sred[g][1][i];
        float mx = sc[0];
        #pragma unroll
        for (int j = 1; j < M1_; ++j) mx = fmaxf(mx, sc[j]);
        float s = 0.f, ex[M1_];
        #pragma unroll
        for (int j = 0; j < M1_; ++j) { ex[j] = expf(sc[j] - mx); s += ex[j]; }
        const float inv = 1.f / s;
        float sg = 0.f;
        #pragma unroll
        for (int j = 0; j < M1_; ++j) sg += ex[j] * inv * vm[j];
        sSG[g][e] = sg;
    }
    __syncthreads();   // 5

    // ---- phase E: score (group 0 computes; block-wide reduce) ----
    float p2a = 0.f, p2b = 0.f;
    if (g == 0) {
        float cvec[4];
        #pragma unroll
        for (int c = 0; c < 4; ++c)
            cvec[c] = ent_emb[(size_t)gp.center[c][b] * DIM_ + e];
        const float rvec0 = rel_emb[(size_t)rp.center[0][b] * DIM_ + e];
        const float rvec1 = rel_emb[(size_t)rp.center[1][b] * DIM_ + e];
        const float ge = 1.f / (1.f + expf(-gate_e[e]));
        const float gr = 1.f / (1.f + expf(-gate_r[e]));
        const float ph_o = ge * cvec[0] + (1.f - ge) * sSG[0][e];
        const float pt_o = ge * cvec[1] + (1.f - ge) * sSG[1][e];
        const float nh_o = ge * cvec[2] + (1.f - ge) * sSG[2][e];
        const float nt_o = ge * cvec[3] + (1.f - ge) * sSG[3][e];
        const float pr_o = gr * rvec0 + (1.f - gr) * sSG[4][e];
        const float nr_o = gr * rvec1 + (1.f - gr) * sSG[5][e];
        const float pv = ph_o + pr_o - pt_o;
        const float nv = nh_o + nr_o - nt_o;
        p2a = pv * pv; p2b = nv * nv;
    }
    #pragma unroll
    for (int off = 32; off; off >>= 1) {
        p2a += __shfl_xor(p2a, off, 64);
        p2b += __shfl_xor(p2b, off, 64);
    }
    const int wv = threadIdx.x >> 6;
    if ((threadIdx.x & 63) == 0) { sredS[wv][0] = p2a; sredS[wv][1] = p2b; }
    __syncthreads();   // 6
    if (threadIdx.x == 0) {
        float sa = 0.f, sb = 0.f;
        #pragma unroll
        for (int w2 = 0; w2 < 12; ++w2) { sa += sredS[w2][0]; sb += sredS[w2][1]; }
        out[b] = sqrtf(sa); out[B_ + b] = sqrtf(sb);
    }
}

extern "C" void kernel_launch(void* const* d_in, const int* in_sizes, int n_in,
                              void* d_out, int out_size, void* d_ws, size_t ws_size,
                              hipStream_t stream)
{
    const float* entity_emb   = (const float*)d_in[0];
    const float* relation_emb = (const float*)d_in[1];
    const float* entity_ctx   = (const float*)d_in[2];
    const float* relation_ctx = (const float*)d_in[3];
    const float* egw          = (const float*)d_in[4];
    const float* rgw          = (const float*)d_in[5];
    const float* gate_e       = (const float*)d_in[6];
    const float* gate_r       = (const float*)d_in[7];
    const float* v_ent        = (const float*)d_in[8];
    const float* v_rel        = (const float*)d_in[9];
    const int* pos_h = (const int*)d_in[10];
    const int* pos_r = (const int*)d_in[11];
    const int* pos_t = (const int*)d_in[12];
    const int* neg_h = (const int*)d_in[13];
    const int* neg_r = (const int*)d_in[14];
    const int* neg_t = (const int*)d_in[15];
    const int* ph_adj = (const int*)d_in[16];
    const int* pt_adj = (const int*)d_in[17];
    const int* nh_adj = (const int*)d_in[18];
    const int* nt_adj = (const int*)d_in[19];
    const int* pr_adj = (const int*)d_in[20];
    const int* nr_adj = (const int*)d_in[21];
    const int* ph_R = (const int*)d_in[22];
    const int* pt_R = (const int*)d_in[23];
    const int* nh_R = (const int*)d_in[24];
    const int* nt_R = (const int*)d_in[25];
    const int* ph_nn = (const int*)d_in[26];
    const int* pt_nn = (const int*)d_in[27];
    const int* nh_nn = (const int*)d_in[28];
    const int* nt_nn = (const int*)d_in[29];
    const float* ph_D = (const float*)d_in[30];
    const float* pt_D = (const float*)d_in[31];
    const float* nh_D = (const float*)d_in[32];
    const float* nt_D = (const float*)d_in[33];
    const float* pr_A = (const float*)d_in[34];
    const float* nr_A = (const float*)d_in[35];

    GatherPtrs gp;
    gp.center[0] = pos_h; gp.center[1] = pos_t; gp.center[2] = neg_h; gp.center[3] = neg_t;
    gp.adj[0] = ph_adj; gp.adj[1] = pt_adj; gp.adj[2] = nh_adj; gp.adj[3] = nt_adj;
    gp.nn[0] = ph_nn; gp.nn[1] = pt_nn; gp.nn[2] = nh_nn; gp.nn[3] = nt_nn;
    gp.Rt[0] = ph_R; gp.Rt[1] = pt_R; gp.Rt[2] = nh_R; gp.Rt[3] = nt_R;
    gp.Dm[0] = ph_D; gp.Dm[1] = pt_D; gp.Dm[2] = nh_D; gp.Dm[3] = nt_D;

    RelPtrs rp;
    rp.center[0] = pos_r; rp.center[1] = neg_r;
    rp.adj2[0] = pr_adj; rp.adj2[1] = nr_adj;
    rp.A[0] = pr_A; rp.A[1] = nr_A;

    char* wsb = (char*)d_ws;
    const size_t partialBytes = (size_t)NQUAD_ * DIM_ * 2;          // 126,877,696
    const size_t eqBytes      = (size_t)NW_ * SLOTS_ * 8;           //   3,293,184
    const size_t dBytes       = (size_t)NW_ * SLOTS_ * 4;           //   1,646,592
    const size_t metaBytes    = 65536;    // cursor | done | nchunks | chunkTab
    const size_t wtBytes      = (size_t)(NW_ + 1) * DIM_ * DIM_ * 2;//   6,619,136
    const size_t fastNeed = partialBytes + eqBytes + dBytes + metaBytes + wtBytes; // ~138.5 MB
    const bool fast = (ws_size >= fastNeed);

    if (fast) {
        _Float16* partial = (_Float16*)wsb;
        int2* itemsEQ = (int2*)(wsb + partialBytes);
        float* itemsD = (float*)(wsb + partialBytes + eqBytes);
        char* meta    = wsb + partialBytes + eqBytes + dBytes;
        int* cursor   = (int*)meta;                 // 201 ints
        int* done     = (int*)(meta + 960);         // 1 int (inside memset'd 1KB)
        int* nchunks  = (int*)(meta + 1024);        // 1 int
        int* chunkTab = (int*)(meta + 2048);        // <= 7945 ints
        unsigned short* WT = (unsigned short*)(wsb + partialBytes + eqBytes + dBytes + metaBytes);

        hipMemsetAsync(cursor, 0, 1024, stream);
        prep_kernel<<<dim3(SCATB_ + WTILES_), dim3(256), 0, stream>>>(
            gp, egw, rgw, WT, cursor, done, itemsEQ, itemsD, chunkTab, nchunks);
        rgcn_gemm<true><<<dim3(MAXCHK_), dim3(256), 0, stream>>>(
            entity_emb, entity_ctx, WT, itemsEQ, itemsD, cursor, chunkTab, nchunks,
            partial, nullptr);
        epi_kernel<true><<<dim3(B_), dim3(768), 0, stream>>>(
            gp, rp, entity_emb, relation_emb, relation_ctx, WT,
            v_ent, v_rel, gate_e, gate_r, partial, nullptr, (float*)d_out);
    } else {
        float* vent = (float*)wsb;
        const size_t ventBytes = (size_t)4 * B_ * M1_ * DIM_ * 4;   // 23,068,672
        unsigned short* WT = (unsigned short*)(wsb + ventBytes);
        int2* itemsEQ = (int2*)(wsb + ventBytes + wtBytes);
        float* itemsD = (float*)(wsb + ventBytes + wtBytes + eqBytes);
        char* meta    = wsb + ventBytes + wtBytes + eqBytes + dBytes;
        int* cursor   = (int*)meta;
        int* done     = (int*)(meta + 960);
        int* nchunks  = (int*)(meta + 1024);
        int* chunkTab = (int*)(meta + 2048);

        hipMemsetAsync(vent, 0, ventBytes, stream);
        hipMemsetAsync(cursor, 0, 1024, stream);
        prep_kernel<<<dim3(SCATB_ + WTILES_), dim3(256), 0, stream>>>(
            gp, egw, rgw, WT, cursor, done, itemsEQ, itemsD, chunkTab, nchunks);
        rgcn_gemm<false><<<dim3(MAXCHK_), dim3(256), 0, stream>>>(
            entity_emb, entity_ctx, WT, itemsEQ, itemsD, cursor, chunkTab, nchunks,
            nullptr, vent);
        epi_kernel<false><<<dim3(B_), dim3(768), 0, stream>>>(
            gp, rp, entity_emb, relation_emb, relation_ctx, WT,
            v_ent, v_rel, gate_e, gate_r, nullptr, vent, (float*)d_out);
    }
}

// Round 14
// 127.648 us; speedup vs baseline: 1.1839x; 1.1839x over previous
//
#include <hip/hip_runtime.h>
#include <math.h>

#define B_   1024
#define M_   10
#define M1_  11
#define DIM_ 128
#define NW_  201                    // real weight rows; r >= 201 -> zero matrix
#define NQUAD_ (4*B_*M1_*M1_)       // 495616 (case,b,j,k) quadruples
#define IPB_  64                    // items per GEMM chunk
#define SLOTS_ 2048                 // item slots per relation type (cnt ~800 max)
#define SCATB_ 242                  // scatter blocks (x256 thr x8 quads)
#define WTILES_ ((NW_+1)*16)        // wconv: one 32x32 tile per block (entity W + Wr)
#define MAXCHK_ (NW_ + NQUAD_/IPB_) // 7945 upper bound on chunks

typedef __attribute__((ext_vector_type(8))) short bf16x8;
typedef __attribute__((ext_vector_type(4))) float f32x4;

struct GatherPtrs {
    const int* center[4];
    const int* adj[4];
    const int* nn[4];
    const int* Rt[4];
    const float* Dm[4];
};

struct RelPtrs {
    const int* center[2];
    const int* adj2[2];
    const float* A[2];
};

__device__ __forceinline__ unsigned short f2bf(float f) {
    union { float f; unsigned u; } v; v.f = f;
    const unsigned r = v.u + 0x7FFFu + ((v.u >> 16) & 1u);   // RNE
    return (unsigned short)(r >> 16);
}

// Batched reduction, WAR-safe for repeated calls (pre-write barrier).
template <int N>
__device__ __forceinline__ void block_reduce_bcast(float (&p)[N], float (*sred)[N],
                                                   int e, float (&sc)[N])
{
    #pragma unroll
    for (int off = 32; off; off >>= 1)
        #pragma unroll
        for (int i = 0; i < N; ++i) p[i] += __shfl_xor(p[i], off, 64);
    __syncthreads();
    if ((e & 63) == 0) {
        #pragma unroll
        for (int i = 0; i < N; ++i) sred[e >> 6][i] = p[i];
    }
    __syncthreads();
    #pragma unroll
    for (int i = 0; i < N; ++i) sc[i] = sred[0][i] + sred[1][i];
}

__device__ __forceinline__ float attn_pool(const float (&vm)[M1_], float o, float ve,
                                           float (*sred)[M1_], int e)
{
    float p[M1_];
    #pragma unroll
    for (int j = 0; j < M1_; ++j) p[j] = fmaxf(vm[j] * o, 0.f) * ve;
    float sc[M1_];
    block_reduce_bcast<M1_>(p, sred, e, sc);
    float mx = sc[0];
    #pragma unroll
    for (int j = 1; j < M1_; ++j) mx = fmaxf(mx, sc[j]);
    float s = 0.f, ex[M1_];
    #pragma unroll
    for (int j = 0; j < M1_; ++j) { ex[j] = expf(sc[j] - mx); s += ex[j]; }
    const float inv = 1.f / s;
    float sg = 0.f;
    #pragma unroll
    for (int j = 0; j < M1_; ++j) sg += ex[j] * inv * vm[j];
    return sg;
}

// ---------------------------------------------------------------------------
// Prep: blocks [0,SCATB_)            : scatter with pre-resolved row/D
//       blocks [SCATB_, +WTILES_)    : weight transpose + bf16 (W and Wr)
// The LAST scatter block to finish also builds the front-packed chunk table
// (reads counts via atomicAdd(.,0) -> coherent across XCDs).
// ---------------------------------------------------------------------------
__global__ __launch_bounds__(256)
void prep_kernel(GatherPtrs gp,
                 const float* __restrict__ W, const float* __restrict__ Wr,
                 unsigned short* __restrict__ WT,
                 int* __restrict__ cursor, int* __restrict__ done,
                 int2* __restrict__ itemsEQ, float* __restrict__ itemsD,
                 int* __restrict__ chunkTab, int* __restrict__ nchunks)
{
    __shared__ int lh[NW_];
    __shared__ int lbase[NW_];
    __shared__ float tile[32][33];
    __shared__ int sLast;
    __shared__ int nchS[NW_];
    __shared__ int bsS[NW_ + 1];
    const int tid = threadIdx.x;
    const int bid = blockIdx.x;

    if (bid < SCATB_) {
        if (tid < NW_) lh[tid] = 0;
        __syncthreads();
        int rr[8], rk[8], ei[8], qv[8];
        float dv[8];
        #pragma unroll
        for (int s = 0; s < 8; ++s) {
            const int idx = bid * 2048 + s * 256 + tid;
            const int c = idx / (B_ * M1_ * M1_);
            const int rem = idx % (B_ * M1_ * M1_);
            const int b = rem / (M1_ * M1_);
            const int jk = rem % (M1_ * M1_);
            const int j = jk / M1_, k = jk % M1_;
            const int n = gp.nn[c][b];
            rr[s] = -1;
            if (j <= n && k <= n) {
                const int r = gp.Rt[c][rem];
                if (r < NW_) {
                    rr[s] = r;
                    rk[s] = atomicAdd(&lh[r], 1);
                    const int eidx = (j == 0) ? gp.center[c][b]
                                              : gp.adj[c][b * M_ + (j - 1)];
                    ei[s] = (eidx << 1) | (j != 0);
                    qv[s] = idx;                       // q == linear quadruple idx
                    dv[s] = gp.Dm[c][rem];
                }
            }
        }
        __syncthreads();
        if (tid < NW_) lbase[tid] = lh[tid] ? atomicAdd(&cursor[tid], lh[tid]) : 0;
        __syncthreads();
        #pragma unroll
        for (int s = 0; s < 8; ++s)
            if (rr[s] >= 0) {
                const int slot = lbase[rr[s]] + rk[s];
                if (slot < SLOTS_) {
                    itemsEQ[rr[s] * SLOTS_ + slot] = make_int2(ei[s], qv[s]);
                    itemsD[rr[s] * SLOTS_ + slot] = dv[s];
                }
            }
        // ---- last-block chunk build ----
        __threadfence();
        __syncthreads();
        if (tid == 0) sLast = (atomicAdd(done, 1) == SCATB_ - 1);
        __syncthreads();
        if (sLast) {
            if (tid < NW_) {
                const int cnt = min(atomicAdd(&cursor[tid], 0), SLOTS_);
                nchS[tid] = (cnt + IPB_ - 1) >> 6;
            }
            __syncthreads();
            if (tid == 0) {
                int acc = 0;
                for (int i = 0; i < NW_; ++i) { bsS[i] = acc; acc += nchS[i]; }
                nchunks[0] = acc;
            }
            __syncthreads();
            if (tid < NW_)
                for (int c = 0; c < nchS[tid]; ++c)
                    chunkTab[bsS[tid] + c] = (tid << 16) | c;
        }
    } else {
        const int tl = bid - SCATB_;
        const int t = tl >> 4, sub = tl & 15;
        const int bd = (sub >> 2) * 32, be = (sub & 3) * 32;
        const float* Ws = (t < NW_) ? (W + (size_t)t * DIM_ * DIM_) : Wr;
        unsigned short* Wd = WT + (size_t)t * DIM_ * DIM_;
        const int tx = tid & 31, ty = tid >> 5;
        #pragma unroll
        for (int r = 0; r < 32; r += 8)
            tile[r + ty][tx] = Ws[(bd + r + ty) * DIM_ + be + tx];
        __syncthreads();
        #pragma unroll
        for (int r = 0; r < 32; r += 8)
            Wd[(be + r + ty) * DIM_ + bd + tx] = f2bf(tile[tx][r + ty]);
    }
}

// ---------------------------------------------------------------------------
// MFMA grouped GEMM: dense front-packed grid (chunkTab), one chunk per block.
// Stage chain: itemsEQ (L2-warm) -> embedding row. No W staging (B-fragments
// straight from L2-resident bf16 WT). D applied in f32 epilogue.
// ---------------------------------------------------------------------------
template <bool FAST>
__global__ __launch_bounds__(256)
void rgcn_gemm(const float* __restrict__ ent_emb,
               const float* __restrict__ ent_ctx,
               const unsigned short* __restrict__ WT,   // [t][e][d] bf16
               const int2* __restrict__ itemsEQ,        // [t][SLOTS_]
               const float* __restrict__ itemsD,        // [t][SLOTS_]
               const int* __restrict__ cursor,
               const int* __restrict__ chunkTab,
               const int* __restrict__ nchunks,
               _Float16* __restrict__ partial,
               float* __restrict__ vent)
{
    __shared__ unsigned short sH[IPB_ * DIM_];   // 16 KB, [item][d] swizzled
    __shared__ int sQ[IPB_];
    __shared__ float sD[IPB_];

    const int bid = blockIdx.x;
    if (bid >= nchunks[0]) return;
    const int ent = chunkTab[bid];
    const int t = ent >> 16, ch = ent & 0xffff;
    const int cnt = min(cursor[t], SLOTS_);
    const int istart = ch * IPB_;
    const int nItems = min(IPB_, cnt - istart);
    const int tid = threadIdx.x;
    const int2* eqBase = itemsEQ + t * SLOTS_ + istart;

    #pragma unroll
    for (int it4 = 0; it4 < 4; ++it4) {
        const int m = it4 * 256 + tid;
        const int it = m >> 4, chd = m & 15;
        uint4 pkd;
        if (it < nItems) {
            const int2 eq = eqBase[it];
            if (chd == 0) {
                sQ[it] = eq.y;
                sD[it] = itemsD[t * SLOTS_ + istart + it];
            }
            const float* srow = (eq.x & 1)
                ? ent_ctx + (size_t)(eq.x >> 1) * DIM_
                : ent_emb + (size_t)(eq.x >> 1) * DIM_;
            const float4* s4 = (const float4*)srow + chd * 2;
            const float4 v0 = s4[0], v1 = s4[1];
            pkd.x = (unsigned)f2bf(v0.x) | ((unsigned)f2bf(v0.y) << 16);
            pkd.y = (unsigned)f2bf(v0.z) | ((unsigned)f2bf(v0.w) << 16);
            pkd.z = (unsigned)f2bf(v1.x) | ((unsigned)f2bf(v1.y) << 16);
            pkd.w = (unsigned)f2bf(v1.z) | ((unsigned)f2bf(v1.w) << 16);
        } else {
            if (chd == 0) { sQ[it] = -1; sD[it] = 0.f; }
            pkd.x = pkd.y = pkd.z = pkd.w = 0u;
        }
        const int so = it * 256 + ((chd * 16) ^ ((it & 7) << 4));
        *reinterpret_cast<uint4*>(reinterpret_cast<char*>(sH) + so) = pkd;
    }
    __syncthreads();

    // 4 waves; wave w owns n-tiles {2w, 2w+1}, all 4 m-tiles.
    const int w = tid >> 6, l = tid & 63;
    const int lr = l & 15, lk = l >> 4;
    const unsigned short* Wp = WT + (size_t)t * DIM_ * DIM_;
    const f32x4 z = {0.f, 0.f, 0.f, 0.f};
    f32x4 acc[4][2];
    #pragma unroll
    for (int mi = 0; mi < 4; ++mi) { acc[mi][0] = z; acc[mi][1] = z; }

    #pragma unroll
    for (int kb = 0; kb < 4; ++kb) {
        const int o = kb * 64 + lk * 16;
        bf16x8 af[4], bfr[2];
        #pragma unroll
        for (int ni = 0; ni < 2; ++ni) {
            const int row = (2 * w + ni) * 16 + lr;
            bfr[ni] = *reinterpret_cast<const bf16x8*>(Wp + (size_t)row * DIM_ + kb * 32 + lk * 8);
        }
        #pragma unroll
        for (int mi = 0; mi < 4; ++mi) {
            const int row = mi * 16 + lr;
            af[mi] = *reinterpret_cast<const bf16x8*>(
                reinterpret_cast<const char*>(sH) + row * 256 + (o ^ ((row & 7) << 4)));
        }
        #pragma unroll
        for (int mi = 0; mi < 4; ++mi)
            #pragma unroll
            for (int ni = 0; ni < 2; ++ni)
                acc[mi][ni] = __builtin_amdgcn_mfma_f32_16x16x32_bf16(
                    af[mi], bfr[ni], acc[mi][ni], 0, 0, 0);
    }

    #pragma unroll
    for (int mi = 0; mi < 4; ++mi) {
        #pragma unroll
        for (int jj = 0; jj < 4; ++jj) {
            const int it = mi * 16 + lk * 4 + jj;
            const int q = sQ[it];
            if (q >= 0) {
                const float d = sD[it];
                #pragma unroll
                for (int ni = 0; ni < 2; ++ni) {
                    const int col = (2 * w + ni) * 16 + lr;
                    const float val = acc[mi][ni][jj] * d;
                    if (FAST) {
                        partial[(size_t)q * DIM_ + col] = (_Float16)val;
                    } else {
                        unsafeAtomicAdd(vent + (size_t)(q / M1_) * DIM_ + col, val);
                    }
                }
            }
        }
    }
}

// ---------------------------------------------------------------------------
// Pool: grid (B, 6). y<4: entity subgraph pool (fp16 partial gather);
// y in {4,5}: relation GCN via MFMA + pool. Short blocks, 6144-way TLP.
// ---------------------------------------------------------------------------
template <bool FAST>
__global__ __launch_bounds__(128)
void pool_kernel(GatherPtrs gp, RelPtrs rp,
                 const float* __restrict__ ent_emb,
                 const float* __restrict__ rel_emb,
                 const float* __restrict__ rel_ctx,
                 const unsigned short* __restrict__ WT,
                 const float* __restrict__ v_ent,
                 const float* __restrict__ v_rel,
                 const _Float16* __restrict__ partial,  // FAST
                 const float* __restrict__ vent,        // !FAST
                 float* __restrict__ sgbuf)
{
    __shared__ float sred[2][M1_];
    const int b = blockIdx.x, c = blockIdx.y, e = threadIdx.x;

    if (c < 4) {
        __shared__ int sRt[M1_ * M1_];
        const int n = gp.nn[c][b];
        if (FAST && e < M1_ * M1_) sRt[e] = gp.Rt[c][b * (M1_ * M1_) + e];
        __syncthreads();

        const float o = ent_emb[(size_t)gp.center[c][b] * DIM_ + e];
        float vm[M1_];
        if (FAST) {
            #pragma unroll
            for (int j = 0; j < M1_; ++j) {
                float s = 0.f;
                if (j <= n) {   // block-uniform branch
                    const int base = (c * B_ + b) * (M1_ * M1_) + j * M1_;
                    #pragma unroll
                    for (int k = 0; k < M1_; ++k) {
                        const float v = (float)partial[(size_t)(base + k) * DIM_ + e];
                        s += (k <= n && sRt[j * M1_ + k] < NW_) ? v : 0.f;
                    }
                    s = fmaxf(s, 0.f);
                }
                vm[j] = s;
            }
        } else {
            const float* vmat = vent + ((size_t)(c * B_ + b)) * M1_ * DIM_;
            #pragma unroll
            for (int j = 0; j < M1_; ++j)
                vm[j] = (j <= n) ? fmaxf(vmat[j * DIM_ + e], 0.f) : 0.f;
        }
        const float sg = attn_pool(vm, o, v_ent[e], sred, e);
        sgbuf[((size_t)c * B_ + b) * DIM_ + e] = sg;
    } else {
        __shared__ float sA[M1_ * M1_];
        __shared__ unsigned short sAH[16 * DIM_];
        __shared__ float sOut[M1_][DIM_];
        const int cse = c - 4;
        const int* adj2 = rp.adj2[cse];

        float h[M1_];
        const float o = rel_emb[(size_t)rp.center[cse][b] * DIM_ + e];
        h[0] = o;
        #pragma unroll
        for (int j = 1; j < M1_; ++j) {
            const int a0 = adj2[((b * M_) + (j - 1)) * 2 + 0];
            const int a1 = adj2[((b * M_) + (j - 1)) * 2 + 1];
            h[j] = rel_ctx[(size_t)a0 * DIM_ + e] + rel_ctx[(size_t)a1 * DIM_ + e];
        }
        if (e < M1_ * M1_) sA[e] = rp.A[cse][b * (M1_ * M1_) + e];
        __syncthreads();

        #pragma unroll
        for (int i = 0; i < M1_; ++i) {
            float s = 0.f;
            #pragma unroll
            for (int jj = 0; jj < M1_; ++jj) s += sA[i * M1_ + jj] * h[jj];
            *reinterpret_cast<unsigned short*>(
                reinterpret_cast<char*>(sAH) + i * 256 + ((2 * e) ^ ((i & 7) << 4))) = f2bf(s);
        }
        #pragma unroll
        for (int i = M1_; i < 16; ++i)
            *reinterpret_cast<unsigned short*>(
                reinterpret_cast<char*>(sAH) + i * 256 + ((2 * e) ^ ((i & 7) << 4))) = 0;
        __syncthreads();

        const int w = e >> 6, l = e & 63;
        const int lr = l & 15, lk = l >> 4;
        const unsigned short* WrT = WT + (size_t)NW_ * DIM_ * DIM_;
        const f32x4 z = {0.f, 0.f, 0.f, 0.f};
        f32x4 acc[4] = {z, z, z, z};
        #pragma unroll
        for (int kb = 0; kb < 4; ++kb) {
            const bf16x8 af = *reinterpret_cast<const bf16x8*>(
                reinterpret_cast<const char*>(sAH) + lr * 256 + ((kb * 64 + lk * 16) ^ ((lr & 7) << 4)));
            #pragma unroll
            for (int ni = 0; ni < 4; ++ni) {
                const int cb = w * 4 + ni;
                const bf16x8 bfr = *reinterpret_cast<const bf16x8*>(
                    WrT + (size_t)(cb * 16 + lr) * DIM_ + kb * 32 + lk * 8);
                acc[ni] = __builtin_amdgcn_mfma_f32_16x16x32_bf16(af, bfr, acc[ni], 0, 0, 0);
            }
        }
        #pragma unroll
        for (int ni = 0; ni < 4; ++ni) {
            const int col = (w * 4 + ni) * 16 + lr;
            #pragma unroll
            for (int jj = 0; jj < 4; ++jj) {
                const int i = lk * 4 + jj;
                if (i < M1_) sOut[i][col] = fmaxf(acc[ni][jj], 0.f);
            }
        }
        __syncthreads();

        float vm[M1_];
        #pragma unroll
        for (int i = 0; i < M1_; ++i) vm[i] = sOut[i][e];
        const float sg = attn_pool(vm, o, v_rel[e], sred, e);
        sgbuf[((size_t)c * B_ + b) * DIM_ + e] = sg;
    }
}

// ---------------------------------------------------------------------------
// Score: gating + two L2 norms
// ---------------------------------------------------------------------------
__global__ __launch_bounds__(128)
void score_kernel(GatherPtrs gp,
                  const float* __restrict__ ent_emb,
                  const float* __restrict__ rel_emb,
                  const int* __restrict__ pos_r, const int* __restrict__ neg_r,
                  const float* __restrict__ gate_e, const float* __restrict__ gate_r,
                  const float* __restrict__ sgbuf,
                  float* __restrict__ out)
{
    __shared__ float sred[2][2];
    const int b = blockIdx.x, e = threadIdx.x;

    float cvec[4], osg[4];
    #pragma unroll
    for (int c = 0; c < 4; ++c) {
        cvec[c] = ent_emb[(size_t)gp.center[c][b] * DIM_ + e];
        osg[c] = sgbuf[((size_t)c * B_ + b) * DIM_ + e];
    }
    const float rvec0 = rel_emb[(size_t)pos_r[b] * DIM_ + e];
    const float rvec1 = rel_emb[(size_t)neg_r[b] * DIM_ + e];
    const float rsg0 = sgbuf[((size_t)4 * B_ + b) * DIM_ + e];
    const float rsg1 = sgbuf[((size_t)5 * B_ + b) * DIM_ + e];

    const float ge = 1.f / (1.f + expf(-gate_e[e]));
    const float gr = 1.f / (1.f + expf(-gate_r[e]));
    const float ph_o = ge * cvec[0] + (1.f - ge) * osg[0];
    const float pt_o = ge * cvec[1] + (1.f - ge) * osg[1];
    const float nh_o = ge * cvec[2] + (1.f - ge) * osg[2];
    const float nt_o = ge * cvec[3] + (1.f - ge) * osg[3];
    const float pr_o = gr * rvec0 + (1.f - gr) * rsg0;
    const float nr_o = gr * rvec1 + (1.f - gr) * rsg1;

    const float pv = ph_o + pr_o - pt_o;
    const float nv = nh_o + nr_o - nt_o;
    float p2[2] = { pv * pv, nv * nv };
    float sc2[2];
    block_reduce_bcast<2>(p2, sred, e, sc2);
    if (e == 0) { out[b] = sqrtf(sc2[0]); out[B_ + b] = sqrtf(sc2[1]); }
}

extern "C" void kernel_launch(void* const* d_in, const int* in_sizes, int n_in,
                              void* d_out, int out_size, void* d_ws, size_t ws_size,
                              hipStream_t stream)
{
    const float* entity_emb   = (const float*)d_in[0];
    const float* relation_emb = (const float*)d_in[1];
    const float* entity_ctx   = (const float*)d_in[2];
    const float* relation_ctx = (const float*)d_in[3];
    const float* egw          = (const float*)d_in[4];
    const float* rgw          = (const float*)d_in[5];
    const float* gate_e       = (const float*)d_in[6];
    const float* gate_r       = (const float*)d_in[7];
    const float* v_ent        = (const float*)d_in[8];
    const float* v_rel        = (const float*)d_in[9];
    const int* pos_h = (const int*)d_in[10];
    const int* pos_r = (const int*)d_in[11];
    const int* pos_t = (const int*)d_in[12];
    const int* neg_h = (const int*)d_in[13];
    const int* neg_r = (const int*)d_in[14];
    const int* neg_t = (const int*)d_in[15];
    const int* ph_adj = (const int*)d_in[16];
    const int* pt_adj = (const int*)d_in[17];
    const int* nh_adj = (const int*)d_in[18];
    const int* nt_adj = (const int*)d_in[19];
    const int* pr_adj = (const int*)d_in[20];
    const int* nr_adj = (const int*)d_in[21];
    const int* ph_R = (const int*)d_in[22];
    const int* pt_R = (const int*)d_in[23];
    const int* nh_R = (const int*)d_in[24];
    const int* nt_R = (const int*)d_in[25];
    const int* ph_nn = (const int*)d_in[26];
    const int* pt_nn = (const int*)d_in[27];
    const int* nh_nn = (const int*)d_in[28];
    const int* nt_nn = (const int*)d_in[29];
    const float* ph_D = (const float*)d_in[30];
    const float* pt_D = (const float*)d_in[31];
    const float* nh_D = (const float*)d_in[32];
    const float* nt_D = (const float*)d_in[33];
    const float* pr_A = (const float*)d_in[34];
    const float* nr_A = (const float*)d_in[35];

    GatherPtrs gp;
    gp.center[0] = pos_h; gp.center[1] = pos_t; gp.center[2] = neg_h; gp.center[3] = neg_t;
    gp.adj[0] = ph_adj; gp.adj[1] = pt_adj; gp.adj[2] = nh_adj; gp.adj[3] = nt_adj;
    gp.nn[0] = ph_nn; gp.nn[1] = pt_nn; gp.nn[2] = nh_nn; gp.nn[3] = nt_nn;
    gp.Rt[0] = ph_R; gp.Rt[1] = pt_R; gp.Rt[2] = nh_R; gp.Rt[3] = nt_R;
    gp.Dm[0] = ph_D; gp.Dm[1] = pt_D; gp.Dm[2] = nh_D; gp.Dm[3] = nt_D;

    RelPtrs rp;
    rp.center[0] = pos_r; rp.center[1] = neg_r;
    rp.adj2[0] = pr_adj; rp.adj2[1] = nr_adj;
    rp.A[0] = pr_A; rp.A[1] = nr_A;

    char* wsb = (char*)d_ws;
    const size_t partialBytes = (size_t)NQUAD_ * DIM_ * 2;          // 126,877,696
    const size_t eqBytes      = (size_t)NW_ * SLOTS_ * 8;           //   3,293,184
    const size_t dBytes       = (size_t)NW_ * SLOTS_ * 4;           //   1,646,592
    const size_t metaBytes    = 65536;    // cursor | done | nchunks | chunkTab
    const size_t wtBytes      = (size_t)(NW_ + 1) * DIM_ * DIM_ * 2;//   6,619,136
    const size_t sgBytes      = (size_t)6 * B_ * DIM_ * 4;          //   3,145,728
    const size_t fastNeed = partialBytes + eqBytes + dBytes + metaBytes + wtBytes; // ~138.5 MB
    const bool fast = (ws_size >= fastNeed);

    if (fast) {
        _Float16* partial = (_Float16*)wsb;
        int2* itemsEQ = (int2*)(wsb + partialBytes);
        float* itemsD = (float*)(wsb + partialBytes + eqBytes);
        char* meta    = wsb + partialBytes + eqBytes + dBytes;
        int* cursor   = (int*)meta;                 // 201 ints
        int* done     = (int*)(meta + 960);         // 1 int (inside memset'd 1KB)
        int* nchunks  = (int*)(meta + 1024);        // 1 int
        int* chunkTab = (int*)(meta + 2048);        // <= 7945 ints
        // WT and sgbuf share this region: sgbuf extent (3.15 MB) < WrT slot
        // offset (6.59 MB); entity W slots dead after rgcn_gemm; WrT consumed
        // by pool before score (stream order).
        char* wsg = wsb + partialBytes + eqBytes + dBytes + metaBytes;
        unsigned short* WT = (unsigned short*)wsg;
        float* sgbuf       = (float*)wsg;

        hipMemsetAsync(cursor, 0, 1024, stream);
        prep_kernel<<<dim3(SCATB_ + WTILES_), dim3(256), 0, stream>>>(
            gp, egw, rgw, WT, cursor, done, itemsEQ, itemsD, chunkTab, nchunks);
        rgcn_gemm<true><<<dim3(MAXCHK_), dim3(256), 0, stream>>>(
            entity_emb, entity_ctx, WT, itemsEQ, itemsD, cursor, chunkTab, nchunks,
            partial, nullptr);
        pool_kernel<true><<<dim3(B_, 6), dim3(128), 0, stream>>>(
            gp, rp, entity_emb, relation_emb, relation_ctx, WT,
            v_ent, v_rel, partial, nullptr, sgbuf);
        score_kernel<<<dim3(B_), dim3(128), 0, stream>>>(
            gp, entity_emb, relation_emb, pos_r, neg_r, gate_e, gate_r, sgbuf, (float*)d_out);
    } else {
        float* vent = (float*)wsb;
        const size_t ventBytes = (size_t)4 * B_ * M1_ * DIM_ * 4;   // 23,068,672
        unsigned short* WT = (unsigned short*)(wsb + ventBytes);
        float* sgbuf  = (float*)(wsb + ventBytes + wtBytes);
        int2* itemsEQ = (int2*)(wsb + ventBytes + wtBytes + sgBytes);
        float* itemsD = (float*)(wsb + ventBytes + wtBytes + sgBytes + eqBytes);
        char* meta    = wsb + ventBytes + wtBytes + sgBytes + eqBytes + dBytes;
        int* cursor   = (int*)meta;
        int* done     = (int*)(meta + 960);
        int* nchunks  = (int*)(meta + 1024);
        int* chunkTab = (int*)(meta + 2048);

        hipMemsetAsync(vent, 0, ventBytes, stream);
        hipMemsetAsync(cursor, 0, 1024, stream);
        prep_kernel<<<dim3(SCATB_ + WTILES_), dim3(256), 0, stream>>>(
            gp, egw, rgw, WT, cursor, done, itemsEQ, itemsD, chunkTab, nchunks);
        rgcn_gemm<false><<<dim3(MAXCHK_), dim3(256), 0, stream>>>(
            entity_emb, entity_ctx, WT, itemsEQ, itemsD, cursor, chunkTab, nchunks,
            nullptr, vent);
        pool_kernel<false><<<dim3(B_, 6), dim3(128), 0, stream>>>(
            gp, rp, entity_emb, relation_emb, relation_ctx, WT,
            v_ent, v_rel, nullptr, vent, sgbuf);
        score_kernel<<<dim3(B_), dim3(128), 0, stream>>>(
            gp, entity_emb, relation_emb, pos_r, neg_r, gate_e, gate_r, sgbuf, (float*)d_out);
    }
}

// Round 15
// 95.326 us; speedup vs baseline: 1.5853x; 1.3391x over previous
//
#include <hip/hip_runtime.h>
#include <math.h>

#define B_   1024
#define M_   10
#define M1_  11
#define DIM_ 128
#define NW_  201                    // real weight rows; r >= 201 -> zero matrix
#define NQUAD_ (4*B_*M1_*M1_)       // 495616 (case,b,j,k) quadruples
#define IPB_  64                    // items per GEMM chunk
#define SLOTS_ 2048                 // item slots per relation type (cnt ~800 max)
#define SCATB_ 242                  // scatter blocks (x256 thr x8 quads)
#define WTILES_ ((NW_+1)*16)        // wconv: one 32x32 tile per block (entity W + Wr)
#define MAXCHK_ (NW_ + NQUAD_/IPB_) // 7945 upper bound on chunks

typedef __attribute__((ext_vector_type(8))) short bf16x8;
typedef __attribute__((ext_vector_type(4))) float f32x4;

struct GatherPtrs {
    const int* center[4];
    const int* adj[4];
    const int* nn[4];
    const int* Rt[4];
    const float* Dm[4];
};

struct RelPtrs {
    const int* center[2];
    const int* adj2[2];
    const float* A[2];
};

__device__ __forceinline__ unsigned short f2bf(float f) {
    union { float f; unsigned u; } v; v.f = f;
    const unsigned r = v.u + 0x7FFFu + ((v.u >> 16) & 1u);   // RNE
    return (unsigned short)(r >> 16);
}

// Batched reduction, WAR-safe for repeated calls (pre-write barrier).
template <int N>
__device__ __forceinline__ void block_reduce_bcast(float (&p)[N], float (*sred)[N],
                                                   int e, float (&sc)[N])
{
    #pragma unroll
    for (int off = 32; off; off >>= 1)
        #pragma unroll
        for (int i = 0; i < N; ++i) p[i] += __shfl_xor(p[i], off, 64);
    __syncthreads();
    if ((e & 63) == 0) {
        #pragma unroll
        for (int i = 0; i < N; ++i) sred[e >> 6][i] = p[i];
    }
    __syncthreads();
    #pragma unroll
    for (int i = 0; i < N; ++i) sc[i] = sred[0][i] + sred[1][i];
}

__device__ __forceinline__ float attn_pool(const float (&vm)[M1_], float o, float ve,
                                           float (*sred)[M1_], int e)
{
    float p[M1_];
    #pragma unroll
    for (int j = 0; j < M1_; ++j) p[j] = fmaxf(vm[j] * o, 0.f) * ve;
    float sc[M1_];
    block_reduce_bcast<M1_>(p, sred, e, sc);
    float mx = sc[0];
    #pragma unroll
    for (int j = 1; j < M1_; ++j) mx = fmaxf(mx, sc[j]);
    float s = 0.f, ex[M1_];
    #pragma unroll
    for (int j = 0; j < M1_; ++j) { ex[j] = expf(sc[j] - mx); s += ex[j]; }
    const float inv = 1.f / s;
    float sg = 0.f;
    #pragma unroll
    for (int j = 0; j < M1_; ++j) sg += ex[j] * inv * vm[j];
    return sg;
}

// ---------------------------------------------------------------------------
// Prep: blocks [0,SCATB_)            : scatter with pre-resolved row/D
//       blocks [SCATB_, +WTILES_)    : weight transpose + bf16 (W and Wr)
// scatter stores per item: itemsEQ = {(eidx<<1)|isCtx, q}, itemsD = Dm value.
// NO cross-block coordination (R14 lesson: per-block __threadfence across
// 8 XCDs cost ~30us; the separate 3us chunkbuild kernel is cheaper).
// ---------------------------------------------------------------------------
__global__ __launch_bounds__(256)
void prep_kernel(GatherPtrs gp,
                 const float* __restrict__ W, const float* __restrict__ Wr,
                 unsigned short* __restrict__ WT,
                 int* __restrict__ cursor,
                 int2* __restrict__ itemsEQ, float* __restrict__ itemsD)
{
    __shared__ int lh[NW_];
    __shared__ int lbase[NW_];
    __shared__ float tile[32][33];
    const int tid = threadIdx.x;
    const int bid = blockIdx.x;

    if (bid < SCATB_) {
        if (tid < NW_) lh[tid] = 0;
        __syncthreads();
        int rr[8], rk[8], ei[8], qv[8];
        float dv[8];
        #pragma unroll
        for (int s = 0; s < 8; ++s) {
            const int idx = bid * 2048 + s * 256 + tid;
            const int c = idx / (B_ * M1_ * M1_);
            const int rem = idx % (B_ * M1_ * M1_);
            const int b = rem / (M1_ * M1_);
            const int jk = rem % (M1_ * M1_);
            const int j = jk / M1_, k = jk % M1_;
            const int n = gp.nn[c][b];
            rr[s] = -1;
            if (j <= n && k <= n) {
                const int r = gp.Rt[c][rem];
                if (r < NW_) {
                    rr[s] = r;
                    rk[s] = atomicAdd(&lh[r], 1);
                    const int eidx = (j == 0) ? gp.center[c][b]
                                              : gp.adj[c][b * M_ + (j - 1)];
                    ei[s] = (eidx << 1) | (j != 0);
                    qv[s] = idx;                       // q == linear quadruple idx
                    dv[s] = gp.Dm[c][rem];
                }
            }
        }
        __syncthreads();
        if (tid < NW_) lbase[tid] = lh[tid] ? atomicAdd(&cursor[tid], lh[tid]) : 0;
        __syncthreads();
        #pragma unroll
        for (int s = 0; s < 8; ++s)
            if (rr[s] >= 0) {
                const int slot = lbase[rr[s]] + rk[s];
                if (slot < SLOTS_) {
                    itemsEQ[rr[s] * SLOTS_ + slot] = make_int2(ei[s], qv[s]);
                    itemsD[rr[s] * SLOTS_ + slot] = dv[s];
                }
            }
    } else {
        const int tl = bid - SCATB_;
        const int t = tl >> 4, sub = tl & 15;
        const int bd = (sub >> 2) * 32, be = (sub & 3) * 32;
        const float* Ws = (t < NW_) ? (W + (size_t)t * DIM_ * DIM_) : Wr;
        unsigned short* Wd = WT + (size_t)t * DIM_ * DIM_;
        const int tx = tid & 31, ty = tid >> 5;
        #pragma unroll
        for (int r = 0; r < 32; r += 8)
            tile[r + ty][tx] = Ws[(bd + r + ty) * DIM_ + be + tx];
        __syncthreads();
        #pragma unroll
        for (int r = 0; r < 32; r += 8)
            Wd[(be + r + ty) * DIM_ + bd + tx] = f2bf(tile[tx][r + ty]);
    }
}

// ---------------------------------------------------------------------------
// Chunk build: front-packed dense chunk table from bucket cursors. 1 block.
// ---------------------------------------------------------------------------
__global__ __launch_bounds__(256)
void chunkbuild_kernel(const int* __restrict__ cursor,
                       int* __restrict__ chunkTab, int* __restrict__ nchunks)
{
    __shared__ int nch[NW_];
    __shared__ int bs[NW_ + 1];
    const int t = threadIdx.x;
    if (t < NW_) {
        const int cnt = min(cursor[t], SLOTS_);
        nch[t] = (cnt + IPB_ - 1) >> 6;
    }
    __syncthreads();
    if (t == 0) {
        int acc = 0;
        for (int i = 0; i < NW_; ++i) { bs[i] = acc; acc += nch[i]; }
        bs[NW_] = acc;
        nchunks[0] = acc;
    }
    __syncthreads();
    if (t < NW_)
        for (int c = 0; c < nch[t]; ++c) chunkTab[bs[t] + c] = (t << 16) | c;
}

// ---------------------------------------------------------------------------
// MFMA grouped GEMM: dense front-packed grid (chunkTab), one chunk per block.
// Stage chain: itemsEQ (L2-warm) -> embedding row. No W staging (B-fragments
// straight from L2-resident bf16 WT). D applied in f32 epilogue.
// ---------------------------------------------------------------------------
template <bool FAST>
__global__ __launch_bounds__(256)
void rgcn_gemm(const float* __restrict__ ent_emb,
               const float* __restrict__ ent_ctx,
               const unsigned short* __restrict__ WT,   // [t][e][d] bf16
               const int2* __restrict__ itemsEQ,        // [t][SLOTS_]
               const float* __restrict__ itemsD,        // [t][SLOTS_]
               const int* __restrict__ cursor,
               const int* __restrict__ chunkTab,
               const int* __restrict__ nchunks,
               _Float16* __restrict__ partial,
               float* __restrict__ vent)
{
    __shared__ unsigned short sH[IPB_ * DIM_];   // 16 KB, [item][d] swizzled
    __shared__ int sQ[IPB_];
    __shared__ float sD[IPB_];

    const int bid = blockIdx.x;
    if (bid >= nchunks[0]) return;
    const int ent = chunkTab[bid];
    const int t = ent >> 16, ch = ent & 0xffff;
    const int cnt = min(cursor[t], SLOTS_);
    const int istart = ch * IPB_;
    const int nItems = min(IPB_, cnt - istart);
    const int tid = threadIdx.x;
    const int2* eqBase = itemsEQ + t * SLOTS_ + istart;

    #pragma unroll
    for (int it4 = 0; it4 < 4; ++it4) {
        const int m = it4 * 256 + tid;
        const int it = m >> 4, chd = m & 15;
        uint4 pkd;
        if (it < nItems) {
            const int2 eq = eqBase[it];
            if (chd == 0) {
                sQ[it] = eq.y;
                sD[it] = itemsD[t * SLOTS_ + istart + it];
            }
            const float* srow = (eq.x & 1)
                ? ent_ctx + (size_t)(eq.x >> 1) * DIM_
                : ent_emb + (size_t)(eq.x >> 1) * DIM_;
            const float4* s4 = (const float4*)srow + chd * 2;
            const float4 v0 = s4[0], v1 = s4[1];
            pkd.x = (unsigned)f2bf(v0.x) | ((unsigned)f2bf(v0.y) << 16);
            pkd.y = (unsigned)f2bf(v0.z) | ((unsigned)f2bf(v0.w) << 16);
            pkd.z = (unsigned)f2bf(v1.x) | ((unsigned)f2bf(v1.y) << 16);
            pkd.w = (unsigned)f2bf(v1.z) | ((unsigned)f2bf(v1.w) << 16);
        } else {
            if (chd == 0) { sQ[it] = -1; sD[it] = 0.f; }
            pkd.x = pkd.y = pkd.z = pkd.w = 0u;
        }
        const int so = it * 256 + ((chd * 16) ^ ((it & 7) << 4));
        *reinterpret_cast<uint4*>(reinterpret_cast<char*>(sH) + so) = pkd;
    }
    __syncthreads();

    // 4 waves; wave w owns n-tiles {2w, 2w+1}, all 4 m-tiles.
    const int w = tid >> 6, l = tid & 63;
    const int lr = l & 15, lk = l >> 4;
    const unsigned short* Wp = WT + (size_t)t * DIM_ * DIM_;
    const f32x4 z = {0.f, 0.f, 0.f, 0.f};
    f32x4 acc[4][2];
    #pragma unroll
    for (int mi = 0; mi < 4; ++mi) { acc[mi][0] = z; acc[mi][1] = z; }

    #pragma unroll
    for (int kb = 0; kb < 4; ++kb) {
        const int o = kb * 64 + lk * 16;
        bf16x8 af[4], bfr[2];
        #pragma unroll
        for (int ni = 0; ni < 2; ++ni) {
            const int row = (2 * w + ni) * 16 + lr;
            bfr[ni] = *reinterpret_cast<const bf16x8*>(Wp + (size_t)row * DIM_ + kb * 32 + lk * 8);
        }
        #pragma unroll
        for (int mi = 0; mi < 4; ++mi) {
            const int row = mi * 16 + lr;
            af[mi] = *reinterpret_cast<const bf16x8*>(
                reinterpret_cast<const char*>(sH) + row * 256 + (o ^ ((row & 7) << 4)));
        }
        #pragma unroll
        for (int mi = 0; mi < 4; ++mi)
            #pragma unroll
            for (int ni = 0; ni < 2; ++ni)
                acc[mi][ni] = __builtin_amdgcn_mfma_f32_16x16x32_bf16(
                    af[mi], bfr[ni], acc[mi][ni], 0, 0, 0);
    }

    #pragma unroll
    for (int mi = 0; mi < 4; ++mi) {
        #pragma unroll
        for (int jj = 0; jj < 4; ++jj) {
            const int it = mi * 16 + lk * 4 + jj;
            const int q = sQ[it];
            if (q >= 0) {
                const float d = sD[it];
                #pragma unroll
                for (int ni = 0; ni < 2; ++ni) {
                    const int col = (2 * w + ni) * 16 + lr;
                    const float val = acc[mi][ni][jj] * d;
                    if (FAST) {
                        partial[(size_t)q * DIM_ + col] = (_Float16)val;
                    } else {
                        unsafeAtomicAdd(vent + (size_t)(q / M1_) * DIM_ + col, val);
                    }
                }
            }
        }
    }
}

// ---------------------------------------------------------------------------
// Pool: grid (B, 6). y<4: entity subgraph pool (fp16 partial gather);
// y in {4,5}: relation GCN via MFMA + pool. Short blocks, 6144-way TLP.
// ---------------------------------------------------------------------------
template <bool FAST>
__global__ __launch_bounds__(128)
void pool_kernel(GatherPtrs gp, RelPtrs rp,
                 const float* __restrict__ ent_emb,
                 const float* __restrict__ rel_emb,
                 const float* __restrict__ rel_ctx,
                 const unsigned short* __restrict__ WT,
                 const float* __restrict__ v_ent,
                 const float* __restrict__ v_rel,
                 const _Float16* __restrict__ partial,  // FAST
                 const float* __restrict__ vent,        // !FAST
                 float* __restrict__ sgbuf)
{
    __shared__ float sred[2][M1_];
    const int b = blockIdx.x, c = blockIdx.y, e = threadIdx.x;

    if (c < 4) {
        __shared__ int sRt[M1_ * M1_];
        const int n = gp.nn[c][b];
        if (FAST && e < M1_ * M1_) sRt[e] = gp.Rt[c][b * (M1_ * M1_) + e];
        __syncthreads();

        const float o = ent_emb[(size_t)gp.center[c][b] * DIM_ + e];
        float vm[M1_];
        if (FAST) {
            #pragma unroll
            for (int j = 0; j < M1_; ++j) {
                float s = 0.f;
                if (j <= n) {   // block-uniform branch
                    const int base = (c * B_ + b) * (M1_ * M1_) + j * M1_;
                    #pragma unroll
                    for (int k = 0; k < M1_; ++k) {
                        const float v = (float)partial[(size_t)(base + k) * DIM_ + e];
                        s += (k <= n && sRt[j * M1_ + k] < NW_) ? v : 0.f;
                    }
                    s = fmaxf(s, 0.f);
                }
                vm[j] = s;
            }
        } else {
            const float* vmat = vent + ((size_t)(c * B_ + b)) * M1_ * DIM_;
            #pragma unroll
            for (int j = 0; j < M1_; ++j)
                vm[j] = (j <= n) ? fmaxf(vmat[j * DIM_ + e], 0.f) : 0.f;
        }
        const float sg = attn_pool(vm, o, v_ent[e], sred, e);
        sgbuf[((size_t)c * B_ + b) * DIM_ + e] = sg;
    } else {
        __shared__ float sA[M1_ * M1_];
        __shared__ unsigned short sAH[16 * DIM_];
        __shared__ float sOut[M1_][DIM_];
        const int cse = c - 4;
        const int* adj2 = rp.adj2[cse];

        float h[M1_];
        const float o = rel_emb[(size_t)rp.center[cse][b] * DIM_ + e];
        h[0] = o;
        #pragma unroll
        for (int j = 1; j < M1_; ++j) {
            const int a0 = adj2[((b * M_) + (j - 1)) * 2 + 0];
            const int a1 = adj2[((b * M_) + (j - 1)) * 2 + 1];
            h[j] = rel_ctx[(size_t)a0 * DIM_ + e] + rel_ctx[(size_t)a1 * DIM_ + e];
        }
        if (e < M1_ * M1_) sA[e] = rp.A[cse][b * (M1_ * M1_) + e];
        __syncthreads();

        #pragma unroll
        for (int i = 0; i < M1_; ++i) {
            float s = 0.f;
            #pragma unroll
            for (int jj = 0; jj < M1_; ++jj) s += sA[i * M1_ + jj] * h[jj];
            *reinterpret_cast<unsigned short*>(
                reinterpret_cast<char*>(sAH) + i * 256 + ((2 * e) ^ ((i & 7) << 4))) = f2bf(s);
        }
        #pragma unroll
        for (int i = M1_; i < 16; ++i)
            *reinterpret_cast<unsigned short*>(
                reinterpret_cast<char*>(sAH) + i * 256 + ((2 * e) ^ ((i & 7) << 4))) = 0;
        __syncthreads();

        const int w = e >> 6, l = e & 63;
        const int lr = l & 15, lk = l >> 4;
        const unsigned short* WrT = WT + (size_t)NW_ * DIM_ * DIM_;
        const f32x4 z = {0.f, 0.f, 0.f, 0.f};
        f32x4 acc[4] = {z, z, z, z};
        #pragma unroll
        for (int kb = 0; kb < 4; ++kb) {
            const bf16x8 af = *reinterpret_cast<const bf16x8*>(
                reinterpret_cast<const char*>(sAH) + lr * 256 + ((kb * 64 + lk * 16) ^ ((lr & 7) << 4)));
            #pragma unroll
            for (int ni = 0; ni < 4; ++ni) {
                const int cb = w * 4 + ni;
                const bf16x8 bfr = *reinterpret_cast<const bf16x8*>(
                    WrT + (size_t)(cb * 16 + lr) * DIM_ + kb * 32 + lk * 8);
                acc[ni] = __builtin_amdgcn_mfma_f32_16x16x32_bf16(af, bfr, acc[ni], 0, 0, 0);
            }
        }
        #pragma unroll
        for (int ni = 0; ni < 4; ++ni) {
            const int col = (w * 4 + ni) * 16 + lr;
            #pragma unroll
            for (int jj = 0; jj < 4; ++jj) {
                const int i = lk * 4 + jj;
                if (i < M1_) sOut[i][col] = fmaxf(acc[ni][jj], 0.f);
            }
        }
        __syncthreads();

        float vm[M1_];
        #pragma unroll
        for (int i = 0; i < M1_; ++i) vm[i] = sOut[i][e];
        const float sg = attn_pool(vm, o, v_rel[e], sred, e);
        sgbuf[((size_t)c * B_ + b) * DIM_ + e] = sg;
    }
}

// ---------------------------------------------------------------------------
// Score: gating + two L2 norms
// ---------------------------------------------------------------------------
__global__ __launch_bounds__(128)
void score_kernel(GatherPtrs gp,
                  const float* __restrict__ ent_emb,
                  const float* __restrict__ rel_emb,
                  const int* __restrict__ pos_r, const int* __restrict__ neg_r,
                  const float* __restrict__ gate_e, const float* __restrict__ gate_r,
                  const float* __restrict__ sgbuf,
                  float* __restrict__ out)
{
    __shared__ float sred[2][2];
    const int b = blockIdx.x, e = threadIdx.x;

    float cvec[4], osg[4];
    #pragma unroll
    for (int c = 0; c < 4; ++c) {
        cvec[c] = ent_emb[(size_t)gp.center[c][b] * DIM_ + e];
        osg[c] = sgbuf[((size_t)c * B_ + b) * DIM_ + e];
    }
    const float rvec0 = rel_emb[(size_t)pos_r[b] * DIM_ + e];
    const float rvec1 = rel_emb[(size_t)neg_r[b] * DIM_ + e];
    const float rsg0 = sgbuf[((size_t)4 * B_ + b) * DIM_ + e];
    const float rsg1 = sgbuf[((size_t)5 * B_ + b) * DIM_ + e];

    const float ge = 1.f / (1.f + expf(-gate_e[e]));
    const float gr = 1.f / (1.f + expf(-gate_r[e]));
    const float ph_o = ge * cvec[0] + (1.f - ge) * osg[0];
    const float pt_o = ge * cvec[1] + (1.f - ge) * osg[1];
    const float nh_o = ge * cvec[2] + (1.f - ge) * osg[2];
    const float nt_o = ge * cvec[3] + (1.f - ge) * osg[3];
    const float pr_o = gr * rvec0 + (1.f - gr) * rsg0;
    const float nr_o = gr * rvec1 + (1.f - gr) * rsg1;

    const float pv = ph_o + pr_o - pt_o;
    const float nv = nh_o + nr_o - nt_o;
    float p2[2] = { pv * pv, nv * nv };
    float sc2[2];
    block_reduce_bcast<2>(p2, sred, e, sc2);
    if (e == 0) { out[b] = sqrtf(sc2[0]); out[B_ + b] = sqrtf(sc2[1]); }
}

extern "C" void kernel_launch(void* const* d_in, const int* in_sizes, int n_in,
                              void* d_out, int out_size, void* d_ws, size_t ws_size,
                              hipStream_t stream)
{
    const float* entity_emb   = (const float*)d_in[0];
    const float* relation_emb = (const float*)d_in[1];
    const float* entity_ctx   = (const float*)d_in[2];
    const float* relation_ctx = (const float*)d_in[3];
    const float* egw          = (const float*)d_in[4];
    const float* rgw          = (const float*)d_in[5];
    const float* gate_e       = (const float*)d_in[6];
    const float* gate_r       = (const float*)d_in[7];
    const float* v_ent        = (const float*)d_in[8];
    const float* v_rel        = (const float*)d_in[9];
    const int* pos_h = (const int*)d_in[10];
    const int* pos_r = (const int*)d_in[11];
    const int* pos_t = (const int*)d_in[12];
    const int* neg_h = (const int*)d_in[13];
    const int* neg_r = (const int*)d_in[14];
    const int* neg_t = (const int*)d_in[15];
    const int* ph_adj = (const int*)d_in[16];
    const int* pt_adj = (const int*)d_in[17];
    const int* nh_adj = (const int*)d_in[18];
    const int* nt_adj = (const int*)d_in[19];
    const int* pr_adj = (const int*)d_in[20];
    const int* nr_adj = (const int*)d_in[21];
    const int* ph_R = (const int*)d_in[22];
    const int* pt_R = (const int*)d_in[23];
    const int* nh_R = (const int*)d_in[24];
    const int* nt_R = (const int*)d_in[25];
    const int* ph_nn = (const int*)d_in[26];
    const int* pt_nn = (const int*)d_in[27];
    const int* nh_nn = (const int*)d_in[28];
    const int* nt_nn = (const int*)d_in[29];
    const float* ph_D = (const float*)d_in[30];
    const float* pt_D = (const float*)d_in[31];
    const float* nh_D = (const float*)d_in[32];
    const float* nt_D = (const float*)d_in[33];
    const float* pr_A = (const float*)d_in[34];
    const float* nr_A = (const float*)d_in[35];

    GatherPtrs gp;
    gp.center[0] = pos_h; gp.center[1] = pos_t; gp.center[2] = neg_h; gp.center[3] = neg_t;
    gp.adj[0] = ph_adj; gp.adj[1] = pt_adj; gp.adj[2] = nh_adj; gp.adj[3] = nt_adj;
    gp.nn[0] = ph_nn; gp.nn[1] = pt_nn; gp.nn[2] = nh_nn; gp.nn[3] = nt_nn;
    gp.Rt[0] = ph_R; gp.Rt[1] = pt_R; gp.Rt[2] = nh_R; gp.Rt[3] = nt_R;
    gp.Dm[0] = ph_D; gp.Dm[1] = pt_D; gp.Dm[2] = nh_D; gp.Dm[3] = nt_D;

    RelPtrs rp;
    rp.center[0] = pos_r; rp.center[1] = neg_r;
    rp.adj2[0] = pr_adj; rp.adj2[1] = nr_adj;
    rp.A[0] = pr_A; rp.A[1] = nr_A;

    char* wsb = (char*)d_ws;
    const size_t partialBytes = (size_t)NQUAD_ * DIM_ * 2;          // 126,877,696
    const size_t eqBytes      = (size_t)NW_ * SLOTS_ * 8;           //   3,293,184
    const size_t dBytes       = (size_t)NW_ * SLOTS_ * 4;           //   1,646,592
    const size_t metaBytes    = 65536;    // cursor(1K) | nchunks | chunkTab(32K)
    const size_t wtBytes      = (size_t)(NW_ + 1) * DIM_ * DIM_ * 2;//   6,619,136
    const size_t sgBytes      = (size_t)6 * B_ * DIM_ * 4;          //   3,145,728
    const size_t fastNeed = partialBytes + eqBytes + dBytes + metaBytes + wtBytes; // ~138.5 MB
    const bool fast = (ws_size >= fastNeed);

    if (fast) {
        _Float16* partial = (_Float16*)wsb;
        int2* itemsEQ = (int2*)(wsb + partialBytes);
        float* itemsD = (float*)(wsb + partialBytes + eqBytes);
        char* meta    = wsb + partialBytes + eqBytes + dBytes;
        int* cursor   = (int*)meta;                 // 201 ints
        int* nchunks  = (int*)(meta + 1024);        // 1 int
        int* chunkTab = (int*)(meta + 2048);        // <= 7945 ints
        // WT and sgbuf share this region: sgbuf extent (3.15 MB) < WrT slot
        // offset (6.59 MB); entity W slots dead after rgcn_gemm (stream order).
        char* wsg = wsb + partialBytes + eqBytes + dBytes + metaBytes;
        unsigned short* WT = (unsigned short*)wsg;
        float* sgbuf       = (float*)wsg;

        hipMemsetAsync(cursor, 0, 1024, stream);
        prep_kernel<<<dim3(SCATB_ + WTILES_), dim3(256), 0, stream>>>(
            gp, egw, rgw, WT, cursor, itemsEQ, itemsD);
        chunkbuild_kernel<<<dim3(1), dim3(256), 0, stream>>>(cursor, chunkTab, nchunks);
        rgcn_gemm<true><<<dim3(MAXCHK_), dim3(256), 0, stream>>>(
            entity_emb, entity_ctx, WT, itemsEQ, itemsD, cursor, chunkTab, nchunks,
            partial, nullptr);
        pool_kernel<true><<<dim3(B_, 6), dim3(128), 0, stream>>>(
            gp, rp, entity_emb, relation_emb, relation_ctx, WT,
            v_ent, v_rel, partial, nullptr, sgbuf);
        score_kernel<<<dim3(B_), dim3(128), 0, stream>>>(
            gp, entity_emb, relation_emb, pos_r, neg_r, gate_e, gate_r, sgbuf, (float*)d_out);
    } else {
        float* vent = (float*)wsb;
        const size_t ventBytes = (size_t)4 * B_ * M1_ * DIM_ * 4;   // 23,068,672
        unsigned short* WT = (unsigned short*)(wsb + ventBytes);
        float* sgbuf  = (float*)(wsb + ventBytes + wtBytes);
        int2* itemsEQ = (int2*)(wsb + ventBytes + wtBytes + sgBytes);
        float* itemsD = (float*)(wsb + ventBytes + wtBytes + sgBytes + eqBytes);
        char* meta    = wsb + ventBytes + wtBytes + sgBytes + eqBytes + dBytes;
        int* cursor   = (int*)meta;
        int* nchunks  = (int*)(meta + 1024);
        int* chunkTab = (int*)(meta + 2048);

        hipMemsetAsync(vent, 0, ventBytes, stream);
        hipMemsetAsync(cursor, 0, 1024, stream);
        prep_kernel<<<dim3(SCATB_ + WTILES_), dim3(256), 0, stream>>>(
            gp, egw, rgw, WT, cursor, itemsEQ, itemsD);
        chunkbuild_kernel<<<dim3(1), dim3(256), 0, stream>>>(cursor, chunkTab, nchunks);
        rgcn_gemm<false><<<dim3(MAXCHK_), dim3(256), 0, stream>>>(
            entity_emb, entity_ctx, WT, itemsEQ, itemsD, cursor, chunkTab, nchunks,
            nullptr, vent);
        pool_kernel<false><<<dim3(B_, 6), dim3(128), 0, stream>>>(
            gp, rp, entity_emb, relation_emb, relation_ctx, WT,
            v_ent, v_rel, nullptr, vent, sgbuf);
        score_kernel<<<dim3(B_), dim3(128), 0, stream>>>(
            gp, entity_emb, relation_emb, pos_r, neg_r, gate_e, gate_r, sgbuf, (float*)d_out);
    }
}